// Round 18
// baseline (1905.032 us; speedup 1.0000x reference)
//
#include <hip/hip_runtime.h>

typedef __attribute__((ext_vector_type(8))) _Float16 f16x8;
typedef __attribute__((ext_vector_type(4))) _Float16 f16x4;
typedef __attribute__((ext_vector_type(4))) float f32x4;
typedef __attribute__((ext_vector_type(4))) unsigned int u32x4;

#define B_SZ 64
#define T_SZ 512
#define I_SZ 512
#define H_SZ 1024
#define G4   4096
#define NBLK 256

// ---------- prep: transpose + gate-interleave weights ----------
// src: [R][1024] fp32 (gate q's U or V). dst: [4096][R] f16, dst[4*n+q][r] = src[r][n]
__global__ void trans_kernel(const float* __restrict__ src, _Float16* __restrict__ dst,
                             int R, int q) {
  __shared__ float tile[64][65];
  const int n0 = blockIdx.x * 64;
  const int r0 = blockIdx.y * 64;
  const int x = threadIdx.x & 63, y = threadIdx.x >> 6;
  #pragma unroll
  for (int it = 0; it < 16; ++it) {
    int r = y * 16 + it;
    tile[r][x] = src[(size_t)(r0 + r) * H_SZ + n0 + x];
  }
  __syncthreads();
  #pragma unroll
  for (int it = 0; it < 16; ++it) {
    int rn = y * 16 + it;
    dst[(size_t)(4 * (n0 + rn) + q) * R + r0 + x] = (_Float16)tile[x][rn];
  }
}

// ---------- prep: interleave bias ----------
__global__ void bias_kernel(const float* __restrict__ b0, const float* __restrict__ b1,
                            const float* __restrict__ b2, const float* __restrict__ b3,
                            float* __restrict__ dst) {
  int g = blockIdx.x * blockDim.x + threadIdx.x;
  if (g >= G4) return;
  int q = g & 3, n = g >> 2;
  const float* s = (q == 0) ? b0 : (q == 1) ? b1 : (q == 2) ? b2 : b3;
  dst[g] = s[n];
}

__device__ __forceinline__ unsigned short f2h(float f) {
  union { unsigned short s; _Float16 h; } c; c.h = (_Float16)f; return c.s;
}

// x prefetch: all 256 threads, 8x16B f32 chunks, linear source (coalesced)
__device__ __forceinline__ void x_issue(const float* x, int b0, int tid, int t, f32x4* xst) {
  #pragma unroll
  for (int j = 0; j < 8; ++j) {
    const int byteoff = j * 4096 + tid * 16;   // f32-slice byte offset
    const int row  = byteoff >> 11;            // 2048 B per f32 row
    const int colb = byteoff & 2047;
    const char* sp = (const char*)x + (((size_t)(b0 + row) * T_SZ + t) * I_SZ) * 4 + colb;
    asm volatile("global_load_dwordx4 %0, %1, off" : "=v"(xst[j]) : "v"(sp) : "memory");
  }
}
// cvt f32->f16 once at stage time; write 8B chunks, XOR-swizzled (16B granules)
__device__ __forceinline__ void x_write(char* xl, int tid, const f32x4* xst) {
  #pragma unroll
  for (int j = 0; j < 8; ++j) {
    const int byteoff = j * 4096 + tid * 16;
    const int row  = byteoff >> 11;
    const int colb = (byteoff & 2047) >> 1;    // f16 byte offset, 8B-aligned
    f16x4 v = { (_Float16)xst[j].x, (_Float16)xst[j].y,
                (_Float16)xst[j].z, (_Float16)xst[j].w };
    *(f16x4*)(xl + (row << 10) + (colb ^ ((row & 7) << 4))) = v;
  }
}

// ---------- persistent recurrence: K-partitioned waves, per-wave flags ----------
// r16 (verified 1762us) with ONE delta: publish is per-wave. Each wave drains
// its own h-stores (vmcnt(0)) and lane0 stores flags[hgrp*4+wv] — the block-wide
// publish barrier is deleted. Consumer wave0: lane L polls ONE dwordx4 = block
// L's 4 wave-flags. Races (pbuf reuse, xlds dbuf) are fenced by the stage-3
// poll barrier: a fast wave cannot pass it until slow waves fully finished the
// previous step.
__global__ __launch_bounds__(256, 1) void lstm_recur(
    const float* __restrict__ x,        // [B][T][I] fp32
    const _Float16* __restrict__ Ubt,   // [4096][512]  row 4n+q = U_q[:,n]
    const _Float16* __restrict__ Vt,    // [4096][1024] row 4n+q = V_q[:,n]
    const float* __restrict__ biasw,    // [4096] interleaved
    float* __restrict__ out,            // hidden_seq | h_T | c_T
    _Float16* __restrict__ hbuf,        // [2][64][1024] f16 double buffer
    unsigned* __restrict__ bar)         // flags: chain bgrp at bar + bgrp*1024
{
  __shared__ __align__(16) char xlds[32768];     // x dbuf [2][16][512] f16, swizzled
  __shared__ __align__(16) float pbuf[4][16][68]; // per-wave K-partials (+4 pad)

  const int tid  = threadIdx.x;
  const int wv   = tid >> 6;      // K-quarter this wave owns
  const int lane = tid & 63;
  const int lc   = lane & 15;     // batch selector (fragment col)
  const int lk   = lane >> 4;     // k-subgroup
  const int blk  = blockIdx.x;
  const int bgrp = blk & 3;       // batch chain (XCD pair)
  const int hgrp = blk >> 2;      // 0..63
  const int b0   = bgrp * 16;
  const int sw   = (lc & 7) << 4; // x read-side swizzle

  unsigned* flags = bar + bgrp * 1024;  // 256 dwords per chain: [hgrp][wv]

  // ---- stationary weights: all 4 col-tiles x this wave's K-quarter ----
  f16x8 bU[16];   // [ct*4+ks], ks<4 : U^T[colg][wv*128 + ks*32 + lk*8]
  f16x8 bV[32];   // [ct*8+ks], ks<8 : V^T[colg][wv*256 + ks*32 + lk*8]
  #pragma unroll
  for (int ct = 0; ct < 4; ++ct) {
    const int colg = hgrp * 64 + ct * 16 + lc;
    const _Float16* up = Ubt + (size_t)colg * I_SZ + wv * 128 + lk * 8;
    #pragma unroll
    for (int ks = 0; ks < 4; ++ks) bU[ct * 4 + ks] = *(const f16x8*)(up + ks * 32);
    const _Float16* vp = Vt + (size_t)colg * H_SZ + wv * 256 + lk * 8;
    #pragma unroll
    for (int ks = 0; ks < 8; ++ks) bV[ct * 8 + ks] = *(const f16x8*)(vp + ks * 32);
  }
  #pragma unroll
  for (int ks = 0; ks < 16; ++ks) asm volatile("" : "+v"(bU[ks]));
  #pragma unroll
  for (int ks = 0; ks < 32; ++ks) asm volatile("" : "+v"(bV[ks]));

  const int nl    = wv * 4 + lk;              // local hidden unit this lane OWNS
  const int n_gl  = hgrp * 16 + nl;
  const int brow  = b0 + lc;
  const f32x4 bias4 = *(const f32x4*)(biasw + hgrp * 64 + nl * 4);
  const size_t HO = (size_t)B_SZ * T_SZ * H_SZ;
  const size_t CO = HO + (size_t)B_SZ * H_SZ;

  float cst = 0.f;   // c-state: one (batch, hidden) pair per lane

  // ---- prime x(0) into xlds[0] ----
  f32x4 xst[8];
  x_issue(x, b0, tid, 0, xst);
  asm volatile("s_waitcnt vmcnt(0)" ::: "memory");
  __builtin_amdgcn_sched_barrier(0);
  x_write(xlds, tid, xst);
  asm volatile("s_waitcnt lgkmcnt(0)" ::: "memory");
  __builtin_amdgcn_s_barrier();
  __builtin_amdgcn_sched_barrier(0);

#define HSTEP(ks, hv) { \
    acc[0] = __builtin_amdgcn_mfma_f32_16x16x32_f16(bV[0 * 8 + (ks)], hv, acc[0], 0, 0, 0); \
    acc[1] = __builtin_amdgcn_mfma_f32_16x16x32_f16(bV[1 * 8 + (ks)], hv, acc[1], 0, 0, 0); \
    acc[2] = __builtin_amdgcn_mfma_f32_16x16x32_f16(bV[2 * 8 + (ks)], hv, acc[2], 0, 0, 0); \
    acc[3] = __builtin_amdgcn_mfma_f32_16x16x32_f16(bV[3 * 8 + (ks)], hv, acc[3], 0, 0, 0); }

  for (int t = 0; t < T_SZ; ++t) {
    const _Float16* hcur  = hbuf + (size_t)(t & 1) * (B_SZ * H_SZ);
    _Float16*       hnext = hbuf + (size_t)((t + 1) & 1) * (B_SZ * H_SZ);
    char* xl_cur = xlds + (size_t)(t & 1) * 16384;
    char* xl_nxt = xlds + (size_t)((t + 1) & 1) * 16384;

    // ---- 1: issue x(t+1) prefetch (in flight across x-proj + poll) ----
    if (t + 1 < T_SZ) x_issue(x, b0, tid, t + 1, xst);

    f32x4 acc[4];
    acc[0] = f32x4{0.f, 0.f, 0.f, 0.f};
    acc[1] = f32x4{0.f, 0.f, 0.f, 0.f};
    acc[2] = f32x4{0.f, 0.f, 0.f, 0.f};
    acc[3] = f32x4{0.f, 0.f, 0.f, 0.f};

    // ---- 2: x projection, K-quarter: one shared x-frag feeds 4 col-tiles ----
    #pragma unroll
    for (int ks = 0; ks < 4; ++ks) {
      const f16x8 xa = *(const f16x8*)(xl_cur + (lc << 10) +
                                       ((wv * 256 + ks * 64 + lk * 16) ^ sw));
      acc[0] = __builtin_amdgcn_mfma_f32_16x16x32_f16(bU[0 * 4 + ks], xa, acc[0], 0, 0, 0);
      acc[1] = __builtin_amdgcn_mfma_f32_16x16x32_f16(bU[1 * 4 + ks], xa, acc[1], 0, 0, 0);
      acc[2] = __builtin_amdgcn_mfma_f32_16x16x32_f16(bU[2 * 4 + ks], xa, acc[2], 0, 0, 0);
      acc[3] = __builtin_amdgcn_mfma_f32_16x16x32_f16(bU[3 * 4 + ks], xa, acc[3], 0, 0, 0);
    }

    // ---- 3: wave0 polls: lane L checks block L's 4 wave-flags (1 dwordx4) ----
    if (t) {
      if (wv == 0) {
        const unsigned* fp = flags + lane * 4;
        u32x4 v;
        do {
          asm volatile("global_load_dwordx4 %0, %1, off sc0 sc1\n\ts_waitcnt vmcnt(0)"
                       : "=&v"(v) : "v"(fp) : "memory");
        } while (__any((v[0] < (unsigned)t) | (v[1] < (unsigned)t) |
                       (v[2] < (unsigned)t) | (v[3] < (unsigned)t)));
      }
      __builtin_amdgcn_s_barrier();
      __builtin_amdgcn_sched_barrier(0);
    }

    // ---- 4: drain x prefetch (uniform; wave0 already at 0) ----
    asm volatile("s_waitcnt vmcnt(0)" ::: "memory");
    __builtin_amdgcn_sched_barrier(0);

    // ---- 5: issue h fragment gather DIRECT to regs (this wave's K-quarter) ----
    f16x8 hv0, hv1, hv2, hv3, hv4, hv5, hv6, hv7;
    {
      const char* hp = (const char*)hcur + (size_t)brow * 2048 + wv * 512 + lk * 16;
      asm volatile("global_load_dwordx4 %0, %1, off sc0 sc1" : "=v"(hv0) : "v"(hp)        : "memory");
      asm volatile("global_load_dwordx4 %0, %1, off sc0 sc1" : "=v"(hv1) : "v"(hp + 64)   : "memory");
      asm volatile("global_load_dwordx4 %0, %1, off sc0 sc1" : "=v"(hv2) : "v"(hp + 128)  : "memory");
      asm volatile("global_load_dwordx4 %0, %1, off sc0 sc1" : "=v"(hv3) : "v"(hp + 192)  : "memory");
      asm volatile("global_load_dwordx4 %0, %1, off sc0 sc1" : "=v"(hv4) : "v"(hp + 256)  : "memory");
      asm volatile("global_load_dwordx4 %0, %1, off sc0 sc1" : "=v"(hv5) : "v"(hp + 320)  : "memory");
      asm volatile("global_load_dwordx4 %0, %1, off sc0 sc1" : "=v"(hv6) : "v"(hp + 384)  : "memory");
      asm volatile("global_load_dwordx4 %0, %1, off sc0 sc1" : "=v"(hv7) : "v"(hp + 448)  : "memory");
    }

    // ---- 6: stage x(t+1) to LDS (DS ops; vmcnt staircase unaffected) ----
    if (t + 1 < T_SZ) x_write(xl_nxt, tid, xst);

    // ---- 7: h projection, vmcnt staircase (load return overlaps MFMA) ----
    asm volatile("s_waitcnt vmcnt(7)" ::: "memory"); __builtin_amdgcn_sched_barrier(0);
    HSTEP(0, hv0);
    asm volatile("s_waitcnt vmcnt(6)" ::: "memory"); __builtin_amdgcn_sched_barrier(0);
    HSTEP(1, hv1);
    asm volatile("s_waitcnt vmcnt(5)" ::: "memory"); __builtin_amdgcn_sched_barrier(0);
    HSTEP(2, hv2);
    asm volatile("s_waitcnt vmcnt(4)" ::: "memory"); __builtin_amdgcn_sched_barrier(0);
    HSTEP(3, hv3);
    asm volatile("s_waitcnt vmcnt(3)" ::: "memory"); __builtin_amdgcn_sched_barrier(0);
    HSTEP(4, hv4);
    asm volatile("s_waitcnt vmcnt(2)" ::: "memory"); __builtin_amdgcn_sched_barrier(0);
    HSTEP(5, hv5);
    asm volatile("s_waitcnt vmcnt(1)" ::: "memory"); __builtin_amdgcn_sched_barrier(0);
    HSTEP(6, hv6);
    asm volatile("s_waitcnt vmcnt(0)" ::: "memory"); __builtin_amdgcn_sched_barrier(0);
    HSTEP(7, hv7);

    // ---- 8: write K-partials; barrier ----
    #pragma unroll
    for (int ct = 0; ct < 4; ++ct)
      *(f32x4*)&pbuf[wv][lc][ct * 16 + lk * 4] = acc[ct];
    asm volatile("s_waitcnt lgkmcnt(0)" ::: "memory");
    __builtin_amdgcn_s_barrier();
    __builtin_amdgcn_sched_barrier(0);

    // ---- 9: owner reduce (4 partials + bias) -> gates, zero shuffles ----
    f32x4 s = bias4;
    #pragma unroll
    for (int w = 0; w < 4; ++w) {
      const f32x4 pv = *(const f32x4*)&pbuf[w][lc][nl * 4];
      s.x += pv.x; s.y += pv.y; s.z += pv.z; s.w += pv.w;
    }
    const float gi = 1.f / (1.f + __expf(-s.x));
    const float gf = 1.f / (1.f + __expf(-s.y));
    const float sg = 1.f / (1.f + __expf(-2.f * s.z));
    const float gg = 2.f * sg - 1.f;                    // tanh
    const float go = 1.f / (1.f + __expf(-s.w));
    const float cn = gf * cst + gi * gg;
    const float sc2 = 1.f / (1.f + __expf(-2.f * cn));
    const float hn = go * (2.f * sc2 - 1.f);
    cst = cn;

    // ---- 10: per-wave publish: h-store, own drain, own flag (NO barrier) ----
    if (t < T_SZ - 1) {
      const unsigned short hv16 = f2h(hn);
      _Float16* hp2 = hnext + (size_t)brow * H_SZ + n_gl;
      asm volatile("global_store_short %0, %1, off sc0 sc1" :: "v"(hp2), "v"(hv16) : "memory");
      asm volatile("s_waitcnt vmcnt(0)" ::: "memory");
      if (lane == 0) {
        const unsigned* fp = flags + hgrp * 4 + wv;
        unsigned tv = (unsigned)(t + 1);
        asm volatile("global_store_dword %0, %1, off sc0 sc1" :: "v"(fp), "v"(tv) : "memory");
      }
    }

    // ---- 11: hidden_seq store (plain, off the critical path) ----
    out[(size_t)brow * (T_SZ * H_SZ) + (size_t)t * H_SZ + n_gl] = hn;
    if (t == T_SZ - 1) {
      out[HO + (size_t)brow * H_SZ + n_gl] = hn;
      out[CO + (size_t)brow * H_SZ + n_gl] = cn;
    }
  }
#undef HSTEP
}

extern "C" void kernel_launch(void* const* d_in, const int* in_sizes, int n_in,
                              void* d_out, int out_size, void* d_ws, size_t ws_size,
                              hipStream_t stream) {
  const float* x = (const float*)d_in[0];
  const float* U[4]  = {(const float*)d_in[1], (const float*)d_in[4],
                        (const float*)d_in[7], (const float*)d_in[10]};
  const float* V[4]  = {(const float*)d_in[2], (const float*)d_in[5],
                        (const float*)d_in[8], (const float*)d_in[11]};
  const float* bb[4] = {(const float*)d_in[3], (const float*)d_in[6],
                        (const float*)d_in[9], (const float*)d_in[12]};
  float* out = (float*)d_out;

  char* p = (char*)d_ws;
  _Float16* Ubt = (_Float16*)p; p += (size_t)G4 * I_SZ * 2;          // 4 MB
  _Float16* Vt  = (_Float16*)p; p += (size_t)G4 * H_SZ * 2;          // 8 MB
  float*    biasw = (float*)p;  p += (size_t)G4 * 4;                 // 16 KB
  _Float16* hbuf  = (_Float16*)p; p += (size_t)2 * B_SZ * H_SZ * 2;  // 256 KB
  unsigned* bar   = (unsigned*)p;                                    // 16 KB

  for (int qq = 0; qq < 4; ++qq)
    hipLaunchKernelGGL(trans_kernel, dim3(16, 8), dim3(256), 0, stream, U[qq], Ubt, I_SZ, qq);
  for (int qq = 0; qq < 4; ++qq)
    hipLaunchKernelGGL(trans_kernel, dim3(16, 16), dim3(256), 0, stream, V[qq], Vt, H_SZ, qq);
  hipLaunchKernelGGL(bias_kernel, dim3(16), dim3(256), 0, stream, bb[0], bb[1], bb[2], bb[3], biasw);

  // h(0) = 0 (buffer 0 read at t=0); flags = 0 (graph-replay safe)
  hipMemsetAsync(hbuf, 0, (size_t)B_SZ * H_SZ * 2, stream);
  hipMemsetAsync(bar, 0, 16384, stream);

  hipLaunchKernelGGL(lstm_recur, dim3(NBLK), dim3(256), 0, stream,
                     x, Ubt, Vt, biasw, out, hbuf, bar);
}

// Round 19
// 1658.990 us; speedup vs baseline: 1.1483x; 1.1483x over previous
//
#include <hip/hip_runtime.h>

typedef __attribute__((ext_vector_type(8))) _Float16 f16x8;
typedef __attribute__((ext_vector_type(4))) _Float16 f16x4;
typedef __attribute__((ext_vector_type(4))) float f32x4;

#define B_SZ 64
#define T_SZ 512
#define I_SZ 512
#define H_SZ 1024
#define G4   4096
#define NBLK 256

// ---------- prep: transpose + gate-interleave weights ----------
// src: [R][1024] fp32 (gate q's U or V). dst: [4096][R] f16, dst[4*n+q][r] = src[r][n]
__global__ void trans_kernel(const float* __restrict__ src, _Float16* __restrict__ dst,
                             int R, int q) {
  __shared__ float tile[64][65];
  const int n0 = blockIdx.x * 64;
  const int r0 = blockIdx.y * 64;
  const int x = threadIdx.x & 63, y = threadIdx.x >> 6;
  #pragma unroll
  for (int it = 0; it < 16; ++it) {
    int r = y * 16 + it;
    tile[r][x] = src[(size_t)(r0 + r) * H_SZ + n0 + x];
  }
  __syncthreads();
  #pragma unroll
  for (int it = 0; it < 16; ++it) {
    int rn = y * 16 + it;
    dst[(size_t)(4 * (n0 + rn) + q) * R + r0 + x] = (_Float16)tile[x][rn];
  }
}

// ---------- prep: interleave bias ----------
__global__ void bias_kernel(const float* __restrict__ b0, const float* __restrict__ b1,
                            const float* __restrict__ b2, const float* __restrict__ b3,
                            float* __restrict__ dst) {
  int g = blockIdx.x * blockDim.x + threadIdx.x;
  if (g >= G4) return;
  int q = g & 3, n = g >> 2;
  const float* s = (q == 0) ? b0 : (q == 1) ? b1 : (q == 2) ? b2 : b3;
  dst[g] = s[n];
}

__device__ __forceinline__ unsigned short f2h(float f) {
  union { unsigned short s; _Float16 h; } c; c.h = (_Float16)f; return c.s;
}

// x prefetch: all 256 threads, 8x16B f32 chunks, linear source (coalesced)
__device__ __forceinline__ void x_issue(const float* x, int b0, int tid, int t, f32x4* xst) {
  #pragma unroll
  for (int j = 0; j < 8; ++j) {
    const int byteoff = j * 4096 + tid * 16;   // f32-slice byte offset
    const int row  = byteoff >> 11;            // 2048 B per f32 row
    const int colb = byteoff & 2047;
    const char* sp = (const char*)x + (((size_t)(b0 + row) * T_SZ + t) * I_SZ) * 4 + colb;
    asm volatile("global_load_dwordx4 %0, %1, off" : "=v"(xst[j]) : "v"(sp) : "memory");
  }
}
// cvt f32->f16 once at stage time; write 8B chunks, XOR-swizzled (16B granules)
__device__ __forceinline__ void x_write(char* xl, int tid, const f32x4* xst) {
  #pragma unroll
  for (int j = 0; j < 8; ++j) {
    const int byteoff = j * 4096 + tid * 16;
    const int row  = byteoff >> 11;
    const int colb = (byteoff & 2047) >> 1;    // f16 byte offset, 8B-aligned
    f16x4 v = { (_Float16)xst[j].x, (_Float16)xst[j].y,
                (_Float16)xst[j].z, (_Float16)xst[j].w };
    *(f16x4*)(xl + (row << 10) + (colb ^ ((row & 7) << 4))) = v;
  }
}

// ---------- persistent recurrence: K-partitioned waves, PER-WAVE dependency ----------
// r16 (verified 1762us) with ONE delta: wave wv's K-quarter [wv*256,wv*256+256)
// is produced by exactly 16 blocks (hgrp' in [wv*16, wv*16+16)). Each wave
// polls only ITS 16 producer flags and proceeds to gather+MFMA independently —
// a fast quarter's compute overlaps a slow producer's publication (skew
// absorbed within the step). Block-wide barriers drop 3 -> 2:
//   A after pbuf write (protects partials), B after h-store drain (orders
//   the single flag + protects pbuf reads vs next-step writes).
__global__ __launch_bounds__(256, 1) void lstm_recur(
    const float* __restrict__ x,        // [B][T][I] fp32
    const _Float16* __restrict__ Ubt,   // [4096][512]  row 4n+q = U_q[:,n]
    const _Float16* __restrict__ Vt,    // [4096][1024] row 4n+q = V_q[:,n]
    const float* __restrict__ biasw,    // [4096] interleaved
    float* __restrict__ out,            // hidden_seq | h_T | c_T
    _Float16* __restrict__ hbuf,        // [2][64][1024] f16 double buffer
    unsigned* __restrict__ bar)         // flags: chain bgrp at bar + bgrp*256
{
  __shared__ __align__(16) char xlds[32768];     // x dbuf [2][16][512] f16, swizzled
  __shared__ __align__(16) float pbuf[4][16][68]; // per-wave K-partials (+4 pad)

  const int tid  = threadIdx.x;
  const int wv   = tid >> 6;      // K-quarter this wave owns
  const int lane = tid & 63;
  const int lc   = lane & 15;     // batch selector (fragment col)
  const int lk   = lane >> 4;     // k-subgroup
  const int blk  = blockIdx.x;
  const int bgrp = blk & 3;       // batch chain (XCD pair)
  const int hgrp = blk >> 2;      // 0..63
  const int b0   = bgrp * 16;
  const int sw   = (lc & 7) << 4; // x read-side swizzle

  unsigned* flags = bar + bgrp * 256;   // 64 dwords per chain

  // ---- stationary weights: all 4 col-tiles x this wave's K-quarter ----
  f16x8 bU[16];   // [ct*4+ks], ks<4 : U^T[colg][wv*128 + ks*32 + lk*8]
  f16x8 bV[32];   // [ct*8+ks], ks<8 : V^T[colg][wv*256 + ks*32 + lk*8]
  #pragma unroll
  for (int ct = 0; ct < 4; ++ct) {
    const int colg = hgrp * 64 + ct * 16 + lc;
    const _Float16* up = Ubt + (size_t)colg * I_SZ + wv * 128 + lk * 8;
    #pragma unroll
    for (int ks = 0; ks < 4; ++ks) bU[ct * 4 + ks] = *(const f16x8*)(up + ks * 32);
    const _Float16* vp = Vt + (size_t)colg * H_SZ + wv * 256 + lk * 8;
    #pragma unroll
    for (int ks = 0; ks < 8; ++ks) bV[ct * 8 + ks] = *(const f16x8*)(vp + ks * 32);
  }
  #pragma unroll
  for (int ks = 0; ks < 16; ++ks) asm volatile("" : "+v"(bU[ks]));
  #pragma unroll
  for (int ks = 0; ks < 32; ++ks) asm volatile("" : "+v"(bV[ks]));

  const int nl    = wv * 4 + lk;              // local hidden unit this lane OWNS
  const int n_gl  = hgrp * 16 + nl;
  const int brow  = b0 + lc;
  const f32x4 bias4 = *(const f32x4*)(biasw + hgrp * 64 + nl * 4);
  const size_t HO = (size_t)B_SZ * T_SZ * H_SZ;
  const size_t CO = HO + (size_t)B_SZ * H_SZ;

  float cst = 0.f;   // c-state: one (batch, hidden) pair per lane

  // ---- prime x(0) into xlds[0] ----
  f32x4 xst[8];
  x_issue(x, b0, tid, 0, xst);
  asm volatile("s_waitcnt vmcnt(0)" ::: "memory");
  __builtin_amdgcn_sched_barrier(0);
  x_write(xlds, tid, xst);
  asm volatile("s_waitcnt lgkmcnt(0)" ::: "memory");
  __builtin_amdgcn_s_barrier();
  __builtin_amdgcn_sched_barrier(0);

#define HSTEP(ks, hv) { \
    acc[0] = __builtin_amdgcn_mfma_f32_16x16x32_f16(bV[0 * 8 + (ks)], hv, acc[0], 0, 0, 0); \
    acc[1] = __builtin_amdgcn_mfma_f32_16x16x32_f16(bV[1 * 8 + (ks)], hv, acc[1], 0, 0, 0); \
    acc[2] = __builtin_amdgcn_mfma_f32_16x16x32_f16(bV[2 * 8 + (ks)], hv, acc[2], 0, 0, 0); \
    acc[3] = __builtin_amdgcn_mfma_f32_16x16x32_f16(bV[3 * 8 + (ks)], hv, acc[3], 0, 0, 0); }

  for (int t = 0; t < T_SZ; ++t) {
    const _Float16* hcur  = hbuf + (size_t)(t & 1) * (B_SZ * H_SZ);
    _Float16*       hnext = hbuf + (size_t)((t + 1) & 1) * (B_SZ * H_SZ);
    char* xl_cur = xlds + (size_t)(t & 1) * 16384;
    char* xl_nxt = xlds + (size_t)((t + 1) & 1) * 16384;

    // ---- 1: issue x(t+1) prefetch (in flight across x-proj + poll) ----
    if (t + 1 < T_SZ) x_issue(x, b0, tid, t + 1, xst);

    f32x4 acc[4];
    acc[0] = f32x4{0.f, 0.f, 0.f, 0.f};
    acc[1] = f32x4{0.f, 0.f, 0.f, 0.f};
    acc[2] = f32x4{0.f, 0.f, 0.f, 0.f};
    acc[3] = f32x4{0.f, 0.f, 0.f, 0.f};

    // ---- 2: x projection, K-quarter: one shared x-frag feeds 4 col-tiles ----
    #pragma unroll
    for (int ks = 0; ks < 4; ++ks) {
      const f16x8 xa = *(const f16x8*)(xl_cur + (lc << 10) +
                                       ((wv * 256 + ks * 64 + lk * 16) ^ sw));
      acc[0] = __builtin_amdgcn_mfma_f32_16x16x32_f16(bU[0 * 4 + ks], xa, acc[0], 0, 0, 0);
      acc[1] = __builtin_amdgcn_mfma_f32_16x16x32_f16(bU[1 * 4 + ks], xa, acc[1], 0, 0, 0);
      acc[2] = __builtin_amdgcn_mfma_f32_16x16x32_f16(bU[2 * 4 + ks], xa, acc[2], 0, 0, 0);
      acc[3] = __builtin_amdgcn_mfma_f32_16x16x32_f16(bU[3 * 4 + ks], xa, acc[3], 0, 0, 0);
    }

    // ---- 3: PER-WAVE poll: this wave's 16 producers only (no barrier!) ----
    // (inline vmcnt(0) also drains this wave's x prefetch — data lands in L2)
    if (t) {
      const unsigned* fp = flags + wv * 16 + (lane & 15);
      unsigned v;
      do {
        asm volatile("global_load_dword %0, %1, off sc0 sc1\n\ts_waitcnt vmcnt(0)"
                     : "=&v"(v) : "v"(fp) : "memory");
      } while (__any(v < (unsigned)t));
      __builtin_amdgcn_sched_barrier(0);
    } else {
      asm volatile("s_waitcnt vmcnt(0)" ::: "memory");
      __builtin_amdgcn_sched_barrier(0);
    }

    // ---- 5: issue h fragment gather DIRECT to regs (this wave's K-quarter) ----
    f16x8 hv0, hv1, hv2, hv3, hv4, hv5, hv6, hv7;
    {
      const char* hp = (const char*)hcur + (size_t)brow * 2048 + wv * 512 + lk * 16;
      asm volatile("global_load_dwordx4 %0, %1, off sc0 sc1" : "=v"(hv0) : "v"(hp)        : "memory");
      asm volatile("global_load_dwordx4 %0, %1, off sc0 sc1" : "=v"(hv1) : "v"(hp + 64)   : "memory");
      asm volatile("global_load_dwordx4 %0, %1, off sc0 sc1" : "=v"(hv2) : "v"(hp + 128)  : "memory");
      asm volatile("global_load_dwordx4 %0, %1, off sc0 sc1" : "=v"(hv3) : "v"(hp + 192)  : "memory");
      asm volatile("global_load_dwordx4 %0, %1, off sc0 sc1" : "=v"(hv4) : "v"(hp + 256)  : "memory");
      asm volatile("global_load_dwordx4 %0, %1, off sc0 sc1" : "=v"(hv5) : "v"(hp + 320)  : "memory");
      asm volatile("global_load_dwordx4 %0, %1, off sc0 sc1" : "=v"(hv6) : "v"(hp + 384)  : "memory");
      asm volatile("global_load_dwordx4 %0, %1, off sc0 sc1" : "=v"(hv7) : "v"(hp + 448)  : "memory");
    }

    // ---- 6: stage x(t+1) to LDS (DS ops; vmcnt staircase unaffected) ----
    if (t + 1 < T_SZ) x_write(xl_nxt, tid, xst);

    // ---- 7: h projection, vmcnt staircase (load return overlaps MFMA) ----
    asm volatile("s_waitcnt vmcnt(7)" ::: "memory"); __builtin_amdgcn_sched_barrier(0);
    HSTEP(0, hv0);
    asm volatile("s_waitcnt vmcnt(6)" ::: "memory"); __builtin_amdgcn_sched_barrier(0);
    HSTEP(1, hv1);
    asm volatile("s_waitcnt vmcnt(5)" ::: "memory"); __builtin_amdgcn_sched_barrier(0);
    HSTEP(2, hv2);
    asm volatile("s_waitcnt vmcnt(4)" ::: "memory"); __builtin_amdgcn_sched_barrier(0);
    HSTEP(3, hv3);
    asm volatile("s_waitcnt vmcnt(3)" ::: "memory"); __builtin_amdgcn_sched_barrier(0);
    HSTEP(4, hv4);
    asm volatile("s_waitcnt vmcnt(2)" ::: "memory"); __builtin_amdgcn_sched_barrier(0);
    HSTEP(5, hv5);
    asm volatile("s_waitcnt vmcnt(1)" ::: "memory"); __builtin_amdgcn_sched_barrier(0);
    HSTEP(6, hv6);
    asm volatile("s_waitcnt vmcnt(0)" ::: "memory"); __builtin_amdgcn_sched_barrier(0);
    HSTEP(7, hv7);

    // ---- 8: write K-partials; barrier A ----
    #pragma unroll
    for (int ct = 0; ct < 4; ++ct)
      *(f32x4*)&pbuf[wv][lc][ct * 16 + lk * 4] = acc[ct];
    asm volatile("s_waitcnt lgkmcnt(0)" ::: "memory");
    __builtin_amdgcn_s_barrier();
    __builtin_amdgcn_sched_barrier(0);

    // ---- 9: owner reduce (4 partials + bias) -> gates, zero shuffles ----
    f32x4 s = bias4;
    #pragma unroll
    for (int w = 0; w < 4; ++w) {
      const f32x4 pv = *(const f32x4*)&pbuf[w][lc][nl * 4];
      s.x += pv.x; s.y += pv.y; s.z += pv.z; s.w += pv.w;
    }
    const float gi = 1.f / (1.f + __expf(-s.x));
    const float gf = 1.f / (1.f + __expf(-s.y));
    const float sg = 1.f / (1.f + __expf(-2.f * s.z));
    const float gg = 2.f * sg - 1.f;                    // tanh
    const float go = 1.f / (1.f + __expf(-s.w));
    const float cn = gf * cst + gi * gg;
    const float sc2 = 1.f / (1.f + __expf(-2.f * cn));
    const float hn = go * (2.f * sc2 - 1.f);
    cst = cn;

    // ---- 10: publish h, drain, barrier B, flag ----
    if (t < T_SZ - 1) {
      const unsigned short hv16 = f2h(hn);
      _Float16* hp2 = hnext + (size_t)brow * H_SZ + n_gl;
      asm volatile("global_store_short %0, %1, off sc0 sc1" :: "v"(hp2), "v"(hv16) : "memory");
    }
    asm volatile("s_waitcnt vmcnt(0)" ::: "memory");
    __builtin_amdgcn_s_barrier();   // B: pbuf reads done + h-stores drained
    if (t < T_SZ - 1 && tid == 64) {
      const unsigned* fp = flags + hgrp;
      unsigned tv = (unsigned)(t + 1);
      asm volatile("global_store_dword %0, %1, off sc0 sc1" :: "v"(fp), "v"(tv) : "memory");
    }

    // ---- 11: hidden_seq store (plain, off the critical path) ----
    out[(size_t)brow * (T_SZ * H_SZ) + (size_t)t * H_SZ + n_gl] = hn;
    if (t == T_SZ - 1) {
      out[HO + (size_t)brow * H_SZ + n_gl] = hn;
      out[CO + (size_t)brow * H_SZ + n_gl] = cn;
    }
  }
#undef HSTEP
}

extern "C" void kernel_launch(void* const* d_in, const int* in_sizes, int n_in,
                              void* d_out, int out_size, void* d_ws, size_t ws_size,
                              hipStream_t stream) {
  const float* x = (const float*)d_in[0];
  const float* U[4]  = {(const float*)d_in[1], (const float*)d_in[4],
                        (const float*)d_in[7], (const float*)d_in[10]};
  const float* V[4]  = {(const float*)d_in[2], (const float*)d_in[5],
                        (const float*)d_in[8], (const float*)d_in[11]};
  const float* bb[4] = {(const float*)d_in[3], (const float*)d_in[6],
                        (const float*)d_in[9], (const float*)d_in[12]};
  float* out = (float*)d_out;

  char* p = (char*)d_ws;
  _Float16* Ubt = (_Float16*)p; p += (size_t)G4 * I_SZ * 2;          // 4 MB
  _Float16* Vt  = (_Float16*)p; p += (size_t)G4 * H_SZ * 2;          // 8 MB
  float*    biasw = (float*)p;  p += (size_t)G4 * 4;                 // 16 KB
  _Float16* hbuf  = (_Float16*)p; p += (size_t)2 * B_SZ * H_SZ * 2;  // 256 KB
  unsigned* bar   = (unsigned*)p;                                    // 16 KB

  for (int qq = 0; qq < 4; ++qq)
    hipLaunchKernelGGL(trans_kernel, dim3(16, 8), dim3(256), 0, stream, U[qq], Ubt, I_SZ, qq);
  for (int qq = 0; qq < 4; ++qq)
    hipLaunchKernelGGL(trans_kernel, dim3(16, 16), dim3(256), 0, stream, V[qq], Vt, H_SZ, qq);
  hipLaunchKernelGGL(bias_kernel, dim3(16), dim3(256), 0, stream, bb[0], bb[1], bb[2], bb[3], biasw);

  // h(0) = 0 (buffer 0 read at t=0); flags = 0 (graph-replay safe)
  hipMemsetAsync(hbuf, 0, (size_t)B_SZ * H_SZ * 2, stream);
  hipMemsetAsync(bar, 0, 16384, stream);

  hipLaunchKernelGGL(lstm_recur, dim3(NBLK), dim3(256), 0, stream,
                     x, Ubt, Vt, biasw, out, hbuf, bar);
}